// Round 3
// baseline (689.839 us; speedup 1.0000x reference)
//
#include <hip/hip_runtime.h>
#include <hip/hip_bf16.h>

typedef short bf16x8 __attribute__((ext_vector_type(8)));
typedef float f32x4 __attribute__((ext_vector_type(4)));

__device__ __forceinline__ unsigned short f2bf(float f) {
  unsigned x = __float_as_uint(f);
  return (unsigned short)((x + 0x7fffu + ((x >> 16) & 1u)) >> 16);  // RNE
}

// fp32 -> bf16, 4 elems/thread
__global__ __launch_bounds__(256)
void cvt_bf16(const float* __restrict__ in, unsigned short* __restrict__ out) {
  int i = (blockIdx.x * 256 + threadIdx.x) * 4;
  float4 v = *(const float4*)(in + i);
  ushort4 o = { f2bf(v.x), f2bf(v.y), f2bf(v.z), f2bf(v.w) };
  *(ushort4*)(out + i) = o;
}

// A [M x K] bf16 row-major, W [K x N] fp32 row-major (converted in staging),
// bias fp32. Block tile BM=128, BN=64, BK=64; 256 thr = 4 waves 2x2 (64x32).
// Mask: N-col-block sj (width CW) live for K in [0, (sj+1)*KROW).
// OUTF32=0: out bf16 (H);  OUTF32=1: out fp32 (d_out).
template<int KROW, int CW, int RELU, int OUTF32>
__global__ __launch_bounds__(256)
void gemm_masked(const unsigned short* __restrict__ A,
                 const float* __restrict__ W,
                 const float* __restrict__ bias,
                 unsigned short* __restrict__ outb,
                 float* __restrict__ outf,
                 int K, int N)
{
  __shared__ unsigned short Xs[128 * 72];  // [m][k], +8 pad
  __shared__ unsigned short Ws[64 * 72];   // [n][k ^ ((n>>3)<<3)], +8 pad

  const int n0 = blockIdx.x * 64;
  const int m0 = blockIdx.y * 128;
  const int Klim = (n0 / CW + 1) * KROW;   // live K extent, multiple of 64

  const int tid  = threadIdx.x;
  const int lane = tid & 63, wave = tid >> 6;
  const int l15  = lane & 15, quad = lane >> 4;
  const int wm0  = (wave & 1) * 64, wn0 = (wave >> 1) * 32;

  const int cg = tid & 7;    // 8-elem column group
  const int rw = tid >> 3;   // row 0..31

  f32x4 acc[4][2];
#pragma unroll
  for (int mi = 0; mi < 4; ++mi)
#pragma unroll
    for (int ni = 0; ni < 2; ++ni)
      acc[mi][ni] = (f32x4){0.f, 0.f, 0.f, 0.f};

  for (int kt = 0; kt < Klim; kt += 64) {
    // ---- global loads into registers ----
    int4 xv[4];                              // A: bf16, 8 elems per int4
    const unsigned short* ap = A + (size_t)(m0 + rw) * K + kt + cg * 8;
#pragma unroll
    for (int i = 0; i < 4; ++i)
      xv[i] = *(const int4*)(ap + (size_t)i * 32 * K);

    float4 wv[2][2];                         // W: fp32, 8 floats per (i)
#pragma unroll
    for (int i = 0; i < 2; ++i) {
      const float* wp = W + (size_t)(kt + i * 32 + rw) * N + n0 + cg * 8;
      wv[i][0] = *(const float4*)wp;
      wv[i][1] = *(const float4*)(wp + 4);
    }

    __syncthreads();  // previous iteration's LDS reads complete

    // ---- LDS stores ----
#pragma unroll
    for (int i = 0; i < 4; ++i)
      *(int4*)(&Xs[(rw + i * 32) * 72 + cg * 8]) = xv[i];

#pragma unroll
    for (int i = 0; i < 2; ++i) {
      const int r = i * 32 + rw;             // k index within tile
      float f[8] = { wv[i][0].x, wv[i][0].y, wv[i][0].z, wv[i][0].w,
                     wv[i][1].x, wv[i][1].y, wv[i][1].z, wv[i][1].w };
#pragma unroll
      for (int j = 0; j < 8; ++j)            // transpose + convert scatter
        Ws[(cg * 8 + j) * 72 + (r ^ (cg << 3))] = f2bf(f[j]);
    }

    __syncthreads();  // stores visible

    // ---- MFMA over the K-tile ----
#pragma unroll
    for (int kk = 0; kk < 64; kk += 32) {
      bf16x8 af[4], bf[2];
#pragma unroll
      for (int mi = 0; mi < 4; ++mi)
        af[mi] = *(const bf16x8*)(&Xs[(wm0 + mi * 16 + l15) * 72 + kk + quad * 8]);
#pragma unroll
      for (int ni = 0; ni < 2; ++ni) {
        const int n_l = wn0 + ni * 16 + l15;
        bf[ni] = *(const bf16x8*)(&Ws[n_l * 72 + ((kk + quad * 8) ^ ((n_l >> 3) << 3))]);
      }
#pragma unroll
      for (int mi = 0; mi < 4; ++mi)
#pragma unroll
        for (int ni = 0; ni < 2; ++ni)
          acc[mi][ni] = __builtin_amdgcn_mfma_f32_16x16x32_bf16(
              af[mi], bf[ni], acc[mi][ni], 0, 0, 0);
    }
  }

  // epilogue: C/D layout col=lane&15, row=quad*4+reg  [m89-verified]
#pragma unroll
  for (int mi = 0; mi < 4; ++mi) {
#pragma unroll
    for (int ni = 0; ni < 2; ++ni) {
      const int n_out = n0 + wn0 + ni * 16 + l15;
      const float bv = bias[n_out];
#pragma unroll
      for (int r = 0; r < 4; ++r) {
        const int m_out = m0 + wm0 + mi * 16 + quad * 4 + r;
        float v = acc[mi][ni][r] + bv;
        if (RELU) v = fmaxf(v, 0.f);
        if (OUTF32) outf[(size_t)m_out * N + n_out] = v;
        else        outb[(size_t)m_out * N + n_out] = f2bf(v);
      }
    }
  }
}

extern "C" void kernel_launch(void* const* d_in, const int* in_sizes, int n_in,
                              void* d_out, int out_size, void* d_ws, size_t ws_size,
                              hipStream_t stream) {
  const float* x  = (const float*)d_in[0];  // [256,64,64] fp32
  const float* W1 = (const float*)d_in[1];  // [4096,8192] fp32
  const float* b1 = (const float*)d_in[2];  // [8192] fp32
  const float* W2 = (const float*)d_in[3];  // [8192,4096] fp32
  const float* b2 = (const float*)d_in[4];  // [4096] fp32
  // d_in[5] = seq_len; dims hardcoded: B=256, S=64, I=64, H=128, O=64

  unsigned short* xb = (unsigned short*)d_ws;                    // 2 MB bf16
  unsigned short* H  = (unsigned short*)((char*)d_ws + (size_t)256*4096*2); // 4 MB bf16
  float* out = (float*)d_out;                                    // [256,4096] fp32

  // x fp32 -> bf16: 256*4096 = 1,048,576 elems, 4/thread
  cvt_bf16<<<dim3(1024), 256, 0, stream>>>(x, xb);

  // GEMM1: xb[256,4096] @ W1[4096,8192], mask 64(K) x 128(N), bias+relu, H bf16
  gemm_masked<64, 128, 1, 0><<<dim3(128, 2), 256, 0, stream>>>(
      xb, W1, b1, H, nullptr, 4096, 8192);

  // GEMM2: H[256,8192] @ W2[8192,4096], mask 128(K) x 64(N), bias, fp32 out
  gemm_masked<128, 64, 0, 1><<<dim3(64, 2), 256, 0, stream>>>(
      H, W2, b2, nullptr, out, 8192, 4096);
}

// Round 4
// 330.827 us; speedup vs baseline: 2.0852x; 2.0852x over previous
//
#include <hip/hip_runtime.h>

typedef short bf16x8 __attribute__((ext_vector_type(8)));
typedef float f32x4 __attribute__((ext_vector_type(4)));

__device__ __forceinline__ unsigned short f2bf(float f) {
  unsigned x = __float_as_uint(f);
  return (unsigned short)((x + 0x7fffu + ((x >> 16) & 1u)) >> 16);  // RNE
}

// d_out[m][n] = b2[n]  (GEMM2 then atomically accumulates on top)
__global__ __launch_bounds__(256)
void init_bias(const float* __restrict__ b, float* __restrict__ out) {
  int i = (blockIdx.x * 256 + threadIdx.x) * 4;
  *(float4*)(out + i) = *(const float4*)(b + (i & 4095));
}

// H_acc[i] = relu(H_acc[i] + b1[i % 8192])   in place (same thread RMW: safe)
__global__ __launch_bounds__(256)
void bias_relu_inplace(float* __restrict__ h, const float* __restrict__ b) {
  int i = (blockIdx.x * 256 + threadIdx.x) * 4;
  float4 v = *(const float4*)(h + i);
  float4 bv = *(const float4*)(b + (i & 8191));
  v.x = fmaxf(v.x + bv.x, 0.f);
  v.y = fmaxf(v.y + bv.y, 0.f);
  v.z = fmaxf(v.z + bv.z, 0.f);
  v.w = fmaxf(v.w + bv.w, 0.f);
  *(float4*)(h + i) = v;
}

// A [M x K] fp32 row-major, W [K x N] fp32 row-major; both converted to bf16
// during LDS staging. Block tile BM=128, BN=64, BK=64; 256 thr = 4 waves 2x2.
// Mask: N-col-block sj (width CW) live for K in [0, (sj+1)*KROW).
// Split-K: block z handles iter range [z*nIter/KS, (z+1)*nIter/KS) of BK=64
// iters; results accumulated with fp32 atomics into `out` (pre-initialized).
template<int KROW, int CW, int KS>
__global__ __launch_bounds__(256, 3)
void gemm_sk(const float* __restrict__ A, const float* __restrict__ W,
             float* __restrict__ out, int K, int N)
{
  __shared__ unsigned short Xs[128 * 72];  // [m][k], +8 pad
  __shared__ unsigned short Ws[64 * 72];   // [n][k ^ ((n>>3)<<3)], +8 pad

  const int n0 = blockIdx.x * 64;
  const int m0 = blockIdx.y * 128;
  const int nIter = ((n0 / CW) + 1) * (KROW / 64);  // live BK-iters for tile
  const int i0 = ((int)blockIdx.z) * nIter / KS;
  const int i1 = ((int)blockIdx.z + 1) * nIter / KS;
  if (i0 == i1) return;                    // uniform exit, before any barrier
  const int kbeg = i0 * 64, kend = i1 * 64;

  const int tid  = threadIdx.x;
  const int lane = tid & 63, wave = tid >> 6;
  const int l15  = lane & 15, quad = lane >> 4;
  const int wm0  = (wave & 1) * 64, wn0 = (wave >> 1) * 32;

  const int cg = tid & 7;    // 8-elem column group
  const int rw = tid >> 3;   // row 0..31

  float4 av[4][2];           // A: 4 rows x 8 floats
  float4 wv[2][2];           // W: 2 rows x 8 floats

  auto loadG = [&](int kt) {
    const float* ap = A + (size_t)(m0 + rw) * K + kt + cg * 8;
#pragma unroll
    for (int i = 0; i < 4; ++i) {
      av[i][0] = *(const float4*)(ap + (size_t)i * 32 * K);
      av[i][1] = *(const float4*)(ap + (size_t)i * 32 * K + 4);
    }
#pragma unroll
    for (int i = 0; i < 2; ++i) {
      const float* wp = W + (size_t)(kt + i * 32 + rw) * N + n0 + cg * 8;
      wv[i][0] = *(const float4*)wp;
      wv[i][1] = *(const float4*)(wp + 4);
    }
  };

  auto storeLDS = [&]() {
#pragma unroll
    for (int i = 0; i < 4; ++i) {           // A rows: convert + one b128 write
      union { unsigned short u[8]; int4 v; } t;
      const float* f = (const float*)&av[i][0];
#pragma unroll
      for (int j = 0; j < 8; ++j) t.u[j] = f2bf(f[j]);
      *(int4*)(&Xs[(rw + i * 32) * 72 + cg * 8]) = t.v;
    }
#pragma unroll
    for (int i = 0; i < 2; ++i) {           // W: transpose+convert scatter
      const int r = i * 32 + rw;
      const float* f = (const float*)&wv[i][0];
#pragma unroll
      for (int j = 0; j < 8; ++j)
        Ws[(cg * 8 + j) * 72 + (r ^ (cg << 3))] = f2bf(f[j]);
    }
  };

  f32x4 acc[4][2];
#pragma unroll
  for (int mi = 0; mi < 4; ++mi)
#pragma unroll
    for (int ni = 0; ni < 2; ++ni)
      acc[mi][ni] = (f32x4){0.f, 0.f, 0.f, 0.f};

  loadG(kbeg);
  for (int kt = kbeg; kt < kend; kt += 64) {
    __syncthreads();                        // prior tile's LDS reads done
    storeLDS();
    if (kt + 64 < kend) loadG(kt + 64);     // prefetch: overlaps barrier+MFMA
    __syncthreads();                        // stores visible
#pragma unroll
    for (int kk = 0; kk < 64; kk += 32) {
      bf16x8 af[4], bf[2];
#pragma unroll
      for (int mi = 0; mi < 4; ++mi)
        af[mi] = *(const bf16x8*)(&Xs[(wm0 + mi * 16 + l15) * 72 + kk + quad * 8]);
#pragma unroll
      for (int ni = 0; ni < 2; ++ni) {
        const int n_l = wn0 + ni * 16 + l15;
        bf[ni] = *(const bf16x8*)(&Ws[n_l * 72 + ((kk + quad * 8) ^ ((n_l >> 3) << 3))]);
      }
#pragma unroll
      for (int mi = 0; mi < 4; ++mi)
#pragma unroll
        for (int ni = 0; ni < 2; ++ni)
          acc[mi][ni] = __builtin_amdgcn_mfma_f32_16x16x32_bf16(
              af[mi], bf[ni], acc[mi][ni], 0, 0, 0);
    }
  }

  // epilogue: C/D layout col=lane&15, row=quad*4+reg; fp32 atomic accumulate
#pragma unroll
  for (int mi = 0; mi < 4; ++mi) {
#pragma unroll
    for (int ni = 0; ni < 2; ++ni) {
      const int n_out = n0 + wn0 + ni * 16 + l15;
#pragma unroll
      for (int r = 0; r < 4; ++r) {
        const int m_out = m0 + wm0 + mi * 16 + quad * 4 + r;
        atomicAdd(&out[(size_t)m_out * N + n_out], acc[mi][ni][r]);
      }
    }
  }
}

extern "C" void kernel_launch(void* const* d_in, const int* in_sizes, int n_in,
                              void* d_out, int out_size, void* d_ws, size_t ws_size,
                              hipStream_t stream) {
  const float* x  = (const float*)d_in[0];  // [256,64,64] fp32
  const float* W1 = (const float*)d_in[1];  // [4096,8192] fp32
  const float* b1 = (const float*)d_in[2];  // [8192] fp32
  const float* W2 = (const float*)d_in[3];  // [8192,4096] fp32
  const float* b2 = (const float*)d_in[4];  // [4096] fp32
  // d_in[5] = seq_len; dims hardcoded: B=256, S=64, I=64, H=128, O=64

  float* H_acc = (float*)d_ws;              // [256, 8192] fp32 = 8 MB
  float* out   = (float*)d_out;             // [256, 4096] fp32

  hipMemsetAsync(H_acc, 0, (size_t)256 * 8192 * sizeof(float), stream);
  init_bias<<<dim3(1024), 256, 0, stream>>>(b2, out);

  // GEMM1: x[256,4096] @ W1[4096,8192], mask 64(K) x 128(N), split-K x4
  gemm_sk<64, 128, 4><<<dim3(128, 2, 4), 256, 0, stream>>>(
      x, W1, H_acc, 4096, 8192);

  // H = relu(H_acc + b1), in place; 2M elems
  bias_relu_inplace<<<dim3(2048), 256, 0, stream>>>(H_acc, b1);

  // GEMM2: H[256,8192] @ W2[8192,4096], mask 128(K) x 64(N), split-K x8,
  // accumulates straight into d_out (pre-filled with b2)
  gemm_sk<128, 64, 8><<<dim3(64, 2, 8), 256, 0, stream>>>(
      H_acc, W2, out, 8192, 4096);
}